// Round 5
// baseline (615.428 us; speedup 1.0000x reference)
//
#include <hip/hip_runtime.h>
#include <hip/hip_bf16.h>
#include <cstdint>
#include <math.h>

// SEDformer block: BN-folded bf16 MFMA GEMMs + in-place chunked EMA scan + RFF linear attention.
// L=2048 BS=16 D=512 H=8 DH=64 R=48 HID=2048; rows NR = L*BS = 32768.
// R5: gemm256 with TRUE counted-vmcnt pipeline: whole-tile staging at boundaries,
// s_waitcnt vmcnt(8) (never 0 in loop), 2 barriers/tile, no intra-tile barriers.

typedef float  f32x4 __attribute__((ext_vector_type(4)));
typedef short  s16x8 __attribute__((ext_vector_type(8)));
typedef unsigned short u16x4 __attribute__((ext_vector_type(4)));

#define DEV static __device__ __forceinline__

constexpr int NR = 32768;          // L*BS

DEV float us2f(unsigned short u) {
  union { unsigned int i; float f; } z; z.i = ((unsigned int)u) << 16; return z.f;
}
DEV unsigned short f2bits(float f) {          // RNE f32 -> bf16 bits
  unsigned int u = __builtin_bit_cast(unsigned int, f);
  unsigned int r = u + 0x7fffu + ((u >> 16) & 1u);
  return (unsigned short)(r >> 16);
}

DEV void gload_lds16(const void* g, void* l) {
  __builtin_amdgcn_global_load_lds((__attribute__((address_space(1))) void*)g,
                                   (__attribute__((address_space(3))) void*)l, 16, 0, 0);
}

// ---------------- param prep: BN scale/shift + membrane betas ----------------
struct PrepArgs {
  const float *g[7], *b[7], *m[7], *v[7];   // bn1,bnq,bnk,bnv,bn2,bnf1,bnf2
  const float *wtq, *wtk;
  float *s[7], *t[7];
  float *betaq, *betak;
};

__global__ void prep_vectors(PrepArgs a) {
  int i = blockIdx.x * 256 + threadIdx.x;   // 0..2047
  const int dims[7] = {512, 512, 512, 512, 512, 2048, 512};
  #pragma unroll
  for (int k = 0; k < 7; ++k) {
    if (i < dims[k]) {
      float sc = a.g[k][i] * rsqrtf(a.v[k][i] + 1e-5f);
      a.s[k][i] = sc;
      a.t[k][i] = a.b[k][i] - a.m[k][i] * sc;
    }
  }
  if (i < 512) {
    float w = a.wtq[i];
    float sp = (w > 20.f) ? w : log1pf(expf(w));
    float be = 1.f - 1.f / (sp + 1.f);
    a.betaq[i] = fminf(fmaxf(be, 0.f), 0.9999f);
    w = a.wtk[i];
    sp = (w > 20.f) ? w : log1pf(expf(w));
    be = 1.f - 1.f / (sp + 1.f);
    a.betak[i] = fminf(fmaxf(be, 0.f), 0.9999f);
  }
}

// -------- fold W[K][N] -> WT bf16 [N][K] with scales; bias[j] = so*(sum_d tin*W + eb) + tout --------
__global__ void fold_wT(const float* __restrict__ W, int K, int Nn,
                        const float* scin, const float* scout,
                        const float* tin, const float* eb, const float* tout,
                        unsigned short* __restrict__ WT, float* bias) {
  int j = blockIdx.x;
  int lane = threadIdx.x;   // 64
  float so = scout ? scout[j] : 1.f;
  float dot = 0.f;
  for (int d = lane; d < K; d += 64) {
    float w = W[(size_t)d * Nn + j];
    float si = scin ? scin[d] : 1.f;
    WT[(size_t)j * K + d] = f2bits(w * si * so);
    if (tin) dot += tin[d] * w;
  }
  if (bias) {
    #pragma unroll
    for (int off = 32; off >= 1; off >>= 1) dot += __shfl_xor(dot, off);
    if (lane == 0) bias[j] = so * (dot + (eb ? eb[j] : 0.f)) + (tout ? tout[j] : 0.f);
  }
}

// ---------------- cast x f32 -> bf16 ----------------
__global__ void cast_x(const float* __restrict__ x, unsigned short* __restrict__ xb, int n) {
  int i = (blockIdx.x * blockDim.x + threadIdx.x) * 4;
  if (i >= n) return;
  float4 v = *(const float4*)(x + i);
  u16x4 o = {f2bits(v.x), f2bits(v.y), f2bits(v.z), f2bits(v.w)};
  *(u16x4*)(xb + i) = o;
}

__global__ void zero_f(float* __restrict__ p, int n) {
  int i = blockIdx.x * 256 + threadIdx.x;
  if (i < n) p[i] = 0.f;
}

// ---------------- 256x256 GEMM, counted-vmcnt pipeline ----------------
// MODE 0: outb = bf16(acc+bias)
// MODE 1: r = xres + acc + bias; outf = r; outb = bf16(r)
// MODE 2: outb = bf16(gelu(acc+bias))   (sigmoid-form tanh gelu)
// MODE 3: outf = xres + acc + bias
// LDS swizzle: 16B slot ^= (row & 7) within each 128B row; global source pre-swizzled (involution).
// Pipeline: whole-tile staging (8 gload_lds/thread) issued at tile boundaries into the
// just-freed buffer; s_waitcnt vmcnt(8) waits only the PREVIOUS tile's loads. 2 barriers/tile.
template <int MODE>
__global__ __launch_bounds__(512, 1) void gemm256(
    const unsigned short* __restrict__ A, const unsigned short* __restrict__ BT,
    int K, int Nn, const float* __restrict__ bias, const float* __restrict__ xres,
    float* __restrict__ outf, unsigned short* __restrict__ outb) {
  __shared__ __align__(16) unsigned short Ab[2][256][64];
  __shared__ __align__(16) unsigned short Bb[2][256][64];
  const int tid = threadIdx.x, wid = tid >> 6, lane = tid & 63;
  const int l15 = lane & 15, lg = lane >> 4;
  const int wm = wid >> 2, wn = wid & 3;     // 2 x 4 wave grid; per-wave out 128 x 64
  const int row0 = blockIdx.x * 256, col0 = blockIdx.y * 256;
  const unsigned short* Abase = A + (size_t)row0 * K;
  const unsigned short* Bbase = BT + (size_t)col0 * K;

  auto stTile = [&](int buf, int kt) {   // 8 gload_lds per thread = full 64KB tile pair
    #pragma unroll
    for (int r = 0; r < 4; ++r) {
      int u = r * 512 + tid;
      int row = u >> 3, slot = u & 7;
      gload_lds16(Abase + (size_t)row * K + kt * 64 + ((slot ^ (row & 7)) << 3),
                  &Ab[buf][row][slot << 3]);
    }
    #pragma unroll
    for (int r = 0; r < 4; ++r) {
      int u = r * 512 + tid;
      int row = u >> 3, slot = u & 7;
      gload_lds16(Bbase + (size_t)row * K + kt * 64 + ((slot ^ (row & 7)) << 3),
                  &Bb[buf][row][slot << 3]);
    }
  };

  const f32x4 fz = {0.f, 0.f, 0.f, 0.f};
  f32x4 acc[8][4];
  #pragma unroll
  for (int m = 0; m < 8; ++m)
    #pragma unroll
    for (int n = 0; n < 4; ++n) acc[m][n] = fz;

  const int nt = K >> 6;
  // prologue: stage tiles 0 and 1
  stTile(0, 0);
  if (nt > 1) {
    stTile(1, 1);
    asm volatile("s_waitcnt vmcnt(8)" ::: "memory");   // tile 0 landed; tile 1 in flight
  } else {
    asm volatile("s_waitcnt vmcnt(0)" ::: "memory");
  }
  __builtin_amdgcn_s_barrier();

  s16x8 af[4][2], bf[4][2];
  for (int t = 0; t < nt; ++t) {
    const int cur = t & 1;
    // ---- tile body: no barriers; compiler interleaves ds_read/MFMA via lgkmcnt ----
    #pragma unroll
    for (int m = 0; m < 4; ++m)
      #pragma unroll
      for (int ks = 0; ks < 2; ++ks) {
        int row = wm * 128 + m * 16 + l15;
        af[m][ks] = *(const s16x8*)&Ab[cur][row][((lg + ks * 4) ^ (row & 7)) << 3];
      }
    #pragma unroll
    for (int n = 0; n < 4; ++n)
      #pragma unroll
      for (int ks = 0; ks < 2; ++ks) {
        int row = wn * 64 + n * 16 + l15;
        bf[n][ks] = *(const s16x8*)&Bb[cur][row][((lg + ks * 4) ^ (row & 7)) << 3];
      }
    __builtin_amdgcn_s_setprio(1);
    #pragma unroll
    for (int m = 0; m < 4; ++m)
      #pragma unroll
      for (int n = 0; n < 4; ++n)
        #pragma unroll
        for (int ks = 0; ks < 2; ++ks)
          acc[m][n] = __builtin_amdgcn_mfma_f32_16x16x32_bf16(af[m][ks], bf[n][ks], acc[m][n], 0, 0, 0);
    __builtin_amdgcn_s_setprio(0);
    #pragma unroll
    for (int m = 0; m < 4; ++m)
      #pragma unroll
      for (int ks = 0; ks < 2; ++ks) {
        int row = wm * 128 + 64 + m * 16 + l15;
        af[m][ks] = *(const s16x8*)&Ab[cur][row][((lg + ks * 4) ^ (row & 7)) << 3];
      }
    __builtin_amdgcn_s_setprio(1);
    #pragma unroll
    for (int m = 0; m < 4; ++m)
      #pragma unroll
      for (int n = 0; n < 4; ++n)
        #pragma unroll
        for (int ks = 0; ks < 2; ++ks)
          acc[4 + m][n] = __builtin_amdgcn_mfma_f32_16x16x32_bf16(af[m][ks], bf[n][ks], acc[4 + m][n], 0, 0, 0);
    __builtin_amdgcn_s_setprio(0);
    // ---- boundary: reads of buf[cur] done -> restage it for t+2; counted wait on t+1 ----
    __builtin_amdgcn_s_barrier();            // all waves finished reading buf[cur]
    if (t + 2 < nt) {
      stTile(cur, t + 2);
      asm volatile("s_waitcnt vmcnt(8)" ::: "memory");   // t+1's loads done; t+2's in flight
    } else {
      asm volatile("s_waitcnt vmcnt(0)" ::: "memory");
    }
    __builtin_amdgcn_s_barrier();            // all waves' loads for next tile visible
  }

  #pragma unroll
  for (int mm = 0; mm < 8; ++mm) {
    #pragma unroll
    for (int q = 0; q < 4; ++q) {
      int row = row0 + wm * 128 + mm * 16 + lg * 4 + q;
      #pragma unroll
      for (int n = 0; n < 4; ++n) {
        int col = col0 + wn * 64 + n * 16 + l15;
        float v = acc[mm][n][q] + bias[col];
        size_t idx = (size_t)row * Nn + col;
        if constexpr (MODE == 0) {
          outb[idx] = f2bits(v);
        } else if constexpr (MODE == 1) {
          float r = xres[idx] + v;
          outf[idx] = r;
          outb[idx] = f2bits(r);
        } else if constexpr (MODE == 2) {
          float u2 = v * 1.5957691216f * (1.f + 0.044715f * v * v);
          float gl = v / (1.f + __expf(-u2));
          outb[idx] = f2bits(gl);
        } else {
          outf[idx] = xres[idx] + v;
        }
      }
    }
  }
}

// ---------------- membrane EMA scan over L, IN-PLACE, coalesced ----------------
__global__ __launch_bounds__(1024) void mem_scan2(unsigned short* __restrict__ qkv,
                         const float* __restrict__ betaq, const float* __restrict__ betak) {
  __shared__ float carry[16][64];
  __shared__ float pre[16][64];
  int cg = blockIdx.x & 15, b = blockIdx.x >> 4;
  int w = threadIdx.x >> 6, lane = threadIdx.x & 63;
  int ch = cg * 64 + lane;
  const float beta = (ch < 512) ? betaq[ch] : betak[ch - 512];
  const float om = 1.f - beta;
  unsigned short* base = qkv + (size_t)b * 1536 + ch;
  const size_t rs = 16 * 1536;     // shorts per L-step
  const int l0 = w * 128;

  float m = 0.f;
  for (int i = 0; i < 128; ++i)
    m = beta * m + om * us2f(base[(size_t)(l0 + i) * rs]);
  carry[w][lane] = m;
  __syncthreads();
  if (w == 0) {
    float pw = beta;
    #pragma unroll
    for (int t = 0; t < 7; ++t) pw *= pw;   // beta^128
    float run = 0.f;
    for (int cc = 0; cc < 16; ++cc) {
      pre[cc][lane] = run;
      run = carry[cc][lane] + pw * run;
    }
  }
  __syncthreads();
  m = pre[w][lane];
  for (int i = 0; i < 128; ++i) {
    size_t off = (size_t)(l0 + i) * rs;
    m = beta * m + om * us2f(base[off]);
    base[off] = f2bits(m);
  }
}

// ---------------- transpose v: qkv v-cols -> vT[b,h,dh][L] ----------------
__global__ void transpose_v(const unsigned short* __restrict__ qkv, unsigned short* __restrict__ vT) {
  __shared__ __align__(16) unsigned short tile[64][72];
  int bid = blockIdx.x;
  int lt = bid & 31, h = (bid >> 5) & 7, b = bid >> 8;
  int l0 = lt * 64;
  int tid = threadIdx.x;
  int r = tid >> 2, cg = (tid & 3) * 16;
  const unsigned short* src = qkv + (size_t)((l0 + r) * 16 + b) * 1536 + 1024 + h * 64 + cg;
  *(s16x8*)&tile[r][cg] = *(const s16x8*)(src);
  *(s16x8*)&tile[r][cg + 8] = *(const s16x8*)(src + 8);
  __syncthreads();
  int dh = tid >> 2, lgp = (tid & 3) * 16;
  s16x8 o0, o1;
  #pragma unroll
  for (int j = 0; j < 8; ++j) {
    o0[j] = (short)tile[lgp + j][dh];
    o1[j] = (short)tile[lgp + 8 + j][dh];
  }
  unsigned short* dstp = vT + (size_t)((b * 8 + h) * 64 + dh) * 2048 + l0 + lgp;
  *(s16x8*)dstp = o0;
  *(s16x8*)(dstp + 8) = o1;
}

// ---------------- RFF linear attention phase A: KV + Ksum accumulation ----------------
__global__ __launch_bounds__(512, 1) void attn_A(
    const unsigned short* __restrict__ qkv, const unsigned short* __restrict__ vT,
    const unsigned short* __restrict__ WrT, const float* __restrict__ rffb,
    float* __restrict__ KVg, float* __restrict__ Ksumg) {
  __shared__ float KV[48][64];
  __shared__ float Ksum[48];
  __shared__ __align__(16) unsigned short phiT[8][48][72];

  const int tid = threadIdx.x;
  const int w = tid >> 6, lane = tid & 63, l15 = lane & 15, lg = lane >> 4;
  const int bh = blockIdx.x, b = bh >> 3, h = bh & 7;
  const int half = blockIdx.y;
  const f32x4 fz = {0.f, 0.f, 0.f, 0.f};
  constexpr float ISR = 0.14433756729740643f;   // 1/sqrt(48)

  for (int i = tid; i < 48 * 64; i += 512) (&KV[0][0])[i] = 0.f;
  if (tid < 48) Ksum[tid] = 0.f;
  __syncthreads();

  s16x8 wf[3][2];
  float bias_n[3];
  #pragma unroll
  for (int n = 0; n < 3; ++n) {
    int r = n * 16 + l15;
    bias_n[n] = rffb[h * 48 + r];
    #pragma unroll
    for (int ks = 0; ks < 2; ++ks)
      wf[n][ks] = *(const s16x8*)(WrT + (size_t)(h * 48 + r) * 64 + ks * 32 + lg * 8);
  }

  f32x4 kv[3][4];
  #pragma unroll
  for (int mm = 0; mm < 3; ++mm)
    #pragma unroll
    for (int nn = 0; nn < 4; ++nn) kv[mm][nn] = fz;
  float ks_acc[3] = {0.f, 0.f, 0.f};
  const size_t vbase = (size_t)(b * 8 + h) * 64 * 2048;

  for (int c = half * 16 + w; c < half * 16 + 16; c += 8) {
    const int l0 = c * 64;
    s16x8 kf[4][2];
    #pragma unroll
    for (int m = 0; m < 4; ++m) {
      size_t ro = (size_t)((l0 + m * 16 + l15) * 16 + b) * 1536 + 512 + h * 64;
      #pragma unroll
      for (int ks = 0; ks < 2; ++ks)
        kf[m][ks] = *(const s16x8*)(qkv + ro + ks * 32 + lg * 8);
    }
    f32x4 p[4][3];
    #pragma unroll
    for (int m = 0; m < 4; ++m)
      #pragma unroll
      for (int n = 0; n < 3; ++n) {
        p[m][n] = fz + bias_n[n];
        #pragma unroll
        for (int ks = 0; ks < 2; ++ks)
          p[m][n] = __builtin_amdgcn_mfma_f32_16x16x32_bf16(kf[m][ks], wf[n][ks], p[m][n], 0, 0, 0);
      }
    #pragma unroll
    for (int m = 0; m < 4; ++m)
      #pragma unroll
      for (int n = 0; n < 3; ++n) {
        u16x4 pk;
        #pragma unroll
        for (int q = 0; q < 4; ++q) {
          float pv = p[m][n][q];
          float ph = (pv > 0.f ? pv + 1.000001f : __expf(pv) + 1e-6f) * ISR;
          ks_acc[n] += ph;
          pk[q] = f2bits(ph);
        }
        *(u16x4*)&phiT[w][n * 16 + l15][m * 16 + lg * 4] = pk;
      }
    s16x8 pf[3][2], vf[4][2];
    #pragma unroll
    for (int mm = 0; mm < 3; ++mm)
      #pragma unroll
      for (int ks = 0; ks < 2; ++ks)
        pf[mm][ks] = *(const s16x8*)&phiT[w][mm * 16 + l15][ks * 32 + lg * 8];
    #pragma unroll
    for (int nn = 0; nn < 4; ++nn)
      #pragma unroll
      for (int ks = 0; ks < 2; ++ks)
        vf[nn][ks] = *(const s16x8*)(vT + vbase + (size_t)(nn * 16 + l15) * 2048 + l0 + ks * 32 + lg * 8);
    #pragma unroll
    for (int mm = 0; mm < 3; ++mm)
      #pragma unroll
      for (int nn = 0; nn < 4; ++nn)
        #pragma unroll
        for (int ks = 0; ks < 2; ++ks)
          kv[mm][nn] = __builtin_amdgcn_mfma_f32_16x16x32_bf16(pf[mm][ks], vf[nn][ks], kv[mm][nn], 0, 0, 0);
  }
  #pragma unroll
  for (int n = 0; n < 3; ++n) {
    float t = ks_acc[n];
    t += __shfl_xor(t, 16);
    t += __shfl_xor(t, 32);
    if (lane < 16) atomicAdd(&Ksum[n * 16 + lane], t);
  }
  #pragma unroll
  for (int mm = 0; mm < 3; ++mm)
    #pragma unroll
    for (int nn = 0; nn < 4; ++nn)
      #pragma unroll
      for (int q = 0; q < 4; ++q)
        atomicAdd(&KV[mm * 16 + lg * 4 + q][nn * 16 + l15], kv[mm][nn][q]);
  __syncthreads();

  for (int i = tid; i < 48 * 64; i += 512) atomicAdd(&KVg[(size_t)bh * 3072 + i], (&KV[0][0])[i]);
  if (tid < 48) atomicAdd(&Ksumg[bh * 48 + tid], Ksum[tid]);
}

// ---------------- RFF linear attention phase B: phi_q, num/den, output ----------------
__global__ __launch_bounds__(512, 1) void attn_B(
    const unsigned short* __restrict__ qkv, const unsigned short* __restrict__ WrT,
    const float* __restrict__ rffb, const float* __restrict__ KVg,
    const float* __restrict__ Ksumg, unsigned short* __restrict__ attn) {
  __shared__ __align__(16) unsigned short KVT[80][72];
  __shared__ __align__(16) unsigned short phiQ[8][64][72];

  const int tid = threadIdx.x;
  const int w = tid >> 6, lane = tid & 63, l15 = lane & 15, lg = lane >> 4;
  const int bh = blockIdx.x, b = bh >> 3, h = bh & 7;
  const int half = blockIdx.y;
  const f32x4 fz = {0.f, 0.f, 0.f, 0.f};
  constexpr float ISR = 0.14433756729740643f;   // 1/sqrt(48)

  for (int i = tid; i < 8 * 64 * 72; i += 512) (&phiQ[0][0][0])[i] = 0;
  for (int i = tid; i < 80 * 72; i += 512) {
    int dhe = i / 72, rr = i - dhe * 72;
    float val = 0.f;
    if (rr < 48) {
      if (dhe < 64) val = KVg[(size_t)bh * 3072 + rr * 64 + dhe];
      else if (dhe == 64) val = fmaxf(Ksumg[bh * 48 + rr], 1e-6f);
    }
    (&KVT[0][0])[i] = f2bits(val);
  }
  __syncthreads();

  s16x8 wf[3][2];
  float bias_n[3];
  #pragma unroll
  for (int n = 0; n < 3; ++n) {
    int r = n * 16 + l15;
    bias_n[n] = rffb[h * 48 + r];
    #pragma unroll
    for (int ks = 0; ks < 2; ++ks)
      wf[n][ks] = *(const s16x8*)(WrT + (size_t)(h * 48 + r) * 64 + ks * 32 + lg * 8);
  }

  for (int c = half * 16 + w; c < half * 16 + 16; c += 8) {
    const int l0 = c * 64;
    s16x8 qf[4][2];
    #pragma unroll
    for (int m = 0; m < 4; ++m) {
      size_t ro = (size_t)((l0 + m * 16 + l15) * 16 + b) * 1536 + h * 64;
      #pragma unroll
      for (int ks = 0; ks < 2; ++ks)
        qf[m][ks] = *(const s16x8*)(qkv + ro + ks * 32 + lg * 8);
    }
    f32x4 p[4][3];
    #pragma unroll
    for (int m = 0; m < 4; ++m)
      #pragma unroll
      for (int n = 0; n < 3; ++n) {
        p[m][n] = fz + bias_n[n];
        #pragma unroll
        for (int ks = 0; ks < 2; ++ks)
          p[m][n] = __builtin_amdgcn_mfma_f32_16x16x32_bf16(qf[m][ks], wf[n][ks], p[m][n], 0, 0, 0);
      }
    #pragma unroll
    for (int m = 0; m < 4; ++m)
      #pragma unroll
      for (int n = 0; n < 3; ++n)
        #pragma unroll
        for (int q = 0; q < 4; ++q) {
          float pv = p[m][n][q];
          float ph = (pv > 0.f ? pv + 1.000001f : __expf(pv) + 1e-6f) * ISR;
          phiQ[w][m * 16 + lg * 4 + q][n * 16 + l15] = f2bits(ph);
        }
    s16x8 af[4][2], bv8[5][2];
    #pragma unroll
    for (int m = 0; m < 4; ++m)
      #pragma unroll
      for (int ks = 0; ks < 2; ++ks)
        af[m][ks] = *(const s16x8*)&phiQ[w][m * 16 + l15][ks * 32 + lg * 8];
    #pragma unroll
    for (int n5 = 0; n5 < 5; ++n5)
      #pragma unroll
      for (int ks = 0; ks < 2; ++ks)
        bv8[n5][ks] = *(const s16x8*)&KVT[n5 * 16 + l15][ks * 32 + lg * 8];
    f32x4 o[4][5];
    #pragma unroll
    for (int m = 0; m < 4; ++m)
      #pragma unroll
      for (int n5 = 0; n5 < 5; ++n5) {
        o[m][n5] = fz;
        #pragma unroll
        for (int ks = 0; ks < 2; ++ks)
          o[m][n5] = __builtin_amdgcn_mfma_f32_16x16x32_bf16(af[m][ks], bv8[n5][ks], o[m][n5], 0, 0, 0);
      }
    #pragma unroll
    for (int m = 0; m < 4; ++m)
      #pragma unroll
      for (int q = 0; q < 4; ++q) {
        float den = __shfl(o[m][4][q], lane & 48);
        float inv = 1.f / (den + 1e-6f);
        int gl = l0 + m * 16 + lg * 4 + q;
        size_t ob = (size_t)(gl * 16 + b) * 512 + h * 64;
        #pragma unroll
        for (int n = 0; n < 4; ++n)
          attn[ob + n * 16 + l15] = f2bits(o[m][n][q] * inv);
      }
  }
}

// ---------------- host ----------------
extern "C" void kernel_launch(void* const* d_in, const int* in_sizes, int n_in,
                              void* d_out, int out_size, void* d_ws, size_t ws_size,
                              hipStream_t stream) {
  (void)in_sizes; (void)n_in; (void)out_size; (void)ws_size;
  const float* x = (const float*)d_in[0];
  const float* Wq = (const float*)d_in[29];
  const float* Wk = (const float*)d_in[30];
  const float* Wv = (const float*)d_in[31];
  const float* bv = (const float*)d_in[32];
  const float* Wo = (const float*)d_in[33];
  const float* bo = (const float*)d_in[34];
  const float* wtq = (const float*)d_in[35];
  const float* wtk = (const float*)d_in[36];
  const float* rffW = (const float*)d_in[37];
  const float* rffb = (const float*)d_in[38];
  const float* fc1W = (const float*)d_in[39];
  const float* fc1b = (const float*)d_in[40];
  const float* fc2W = (const float*)d_in[41];
  const float* fc2b = (const float*)d_in[42];

  char* cur = (char*)d_ws;
  auto alloc = [&](size_t bytes) -> char* {
    char* r = cur;
    cur += (bytes + 255) & ~(size_t)255;
    return r;
  };
  float* sv_[7];
  float* tv_[7];
  const int dims[7] = {512, 512, 512, 512, 512, 2048, 512};
  for (int k = 0; k < 7; ++k) {
    sv_[k] = (float*)alloc(dims[k] * 4);
    tv_[k] = (float*)alloc(dims[k] * 4);
  }
  float* betaq = (float*)alloc(512 * 4);
  float* betak = (float*)alloc(512 * 4);
  float* c_qkv = (float*)alloc(1536 * 4);
  float* c1 = (float*)alloc(2048 * 4);
  float* c2 = (float*)alloc(512 * 4);
  float* KVg   = (float*)alloc((size_t)128 * 3072 * 4);
  float* Ksumg = (float*)alloc((size_t)128 * 48 * 4);
  unsigned short* AqkvT = (unsigned short*)alloc((size_t)1536 * 512 * 2);
  unsigned short* WoT   = (unsigned short*)alloc((size_t)512 * 512 * 2);
  unsigned short* A1T   = (unsigned short*)alloc((size_t)2048 * 512 * 2);
  unsigned short* A2T   = (unsigned short*)alloc((size_t)512 * 2048 * 2);
  unsigned short* WrT   = (unsigned short*)alloc((size_t)8 * 48 * 64 * 2);
  // big buffers (qkv and vT MUST be adjacent: g overlays both exactly)
  unsigned short* qkv   = (unsigned short*)alloc((size_t)NR * 1536 * 2);  // 96 MiB
  unsigned short* vT    = (unsigned short*)alloc((size_t)NR * 512 * 2);   // 32 MiB
  unsigned short* xbA   = (unsigned short*)alloc((size_t)NR * 512 * 2);   // 32 MiB: xb then attn-out
  unsigned short* xrb   = (unsigned short*)alloc((size_t)NR * 512 * 2);   // 32 MiB
  unsigned short* xb = xbA;            // bf16(x), dead after QKV GEMM
  unsigned short* attn = xbA;          // attn output (after xb is dead)
  unsigned short* g = qkv;             // fc1-out [NR][2048] bf16 = 128 MiB over qkv+vT (both dead)
  float* xr = (float*)d_out;           // f32 residual stream lives in d_out

  PrepArgs pa;
  for (int k = 0; k < 7; ++k) {
    pa.g[k] = (const float*)d_in[1 + k * 4 + 0];
    pa.b[k] = (const float*)d_in[1 + k * 4 + 1];
    pa.m[k] = (const float*)d_in[1 + k * 4 + 2];
    pa.v[k] = (const float*)d_in[1 + k * 4 + 3];
    pa.s[k] = sv_[k];
    pa.t[k] = tv_[k];
  }
  pa.wtq = wtq; pa.wtk = wtk; pa.betaq = betaq; pa.betak = betak;

  prep_vectors<<<8, 256, 0, stream>>>(pa);
  fold_wT<<<512, 64, 0, stream>>>(Wq, 512, 512, sv_[0], sv_[1], tv_[0], nullptr, tv_[1], AqkvT, c_qkv);
  fold_wT<<<512, 64, 0, stream>>>(Wk, 512, 512, sv_[0], sv_[2], tv_[0], nullptr, tv_[2], AqkvT + 512 * 512, c_qkv + 512);
  fold_wT<<<512, 64, 0, stream>>>(Wv, 512, 512, sv_[0], sv_[3], tv_[0], bv, tv_[3], AqkvT + 1024 * 512, c_qkv + 1024);
  fold_wT<<<512, 64, 0, stream>>>(Wo, 512, 512, nullptr, nullptr, nullptr, nullptr, nullptr, WoT, nullptr);
  fold_wT<<<2048, 64, 0, stream>>>(fc1W, 512, 2048, sv_[4], sv_[5], tv_[4], fc1b, tv_[5], A1T, c1);
  fold_wT<<<512, 64, 0, stream>>>(fc2W, 2048, 512, nullptr, sv_[6], nullptr, fc2b, tv_[6], A2T, c2);
  for (int h = 0; h < 8; ++h)
    fold_wT<<<48, 64, 0, stream>>>(rffW + h * 64 * 48, 64, 48, nullptr, nullptr, nullptr, nullptr, nullptr,
                                   WrT + h * 48 * 64, nullptr);

  cast_x<<<16384, 256, 0, stream>>>(x, xb, NR * 512);
  gemm256<0><<<dim3(128, 6), 512, 0, stream>>>(xb, AqkvT, 512, 1536, c_qkv, nullptr, nullptr, qkv);
  mem_scan2<<<256, 1024, 0, stream>>>(qkv, betaq, betak);
  transpose_v<<<4096, 256, 0, stream>>>(qkv, vT);
  zero_f<<<1536, 256, 0, stream>>>(KVg, 128 * 3072);
  zero_f<<<24, 256, 0, stream>>>(Ksumg, 128 * 48);
  attn_A<<<dim3(128, 2), 512, 0, stream>>>(qkv, vT, WrT, rffb, KVg, Ksumg);
  attn_B<<<dim3(128, 2), 512, 0, stream>>>(qkv, WrT, rffb, KVg, Ksumg, attn);
  gemm256<1><<<dim3(128, 2), 512, 0, stream>>>(attn, WoT, 512, 512, bo, x, xr, xrb);
  gemm256<2><<<dim3(128, 8), 512, 0, stream>>>(xrb, A1T, 512, 2048, c1, nullptr, nullptr, g);
  gemm256<3><<<dim3(128, 2), 512, 0, stream>>>(g, A2T, 2048, 512, c2, xr, (float*)d_out, nullptr);
}

// Round 6
// 563.139 us; speedup vs baseline: 1.0929x; 1.0929x over previous
//
#include <hip/hip_runtime.h>
#include <hip/hip_bf16.h>
#include <cstdint>
#include <math.h>

// SEDformer block: BN-folded bf16 MFMA GEMMs + in-place chunked EMA scan + RFF linear attention.
// L=2048 BS=16 D=512 H=8 DH=64 R=48 HID=2048; rows NR = L*BS = 32768.
// R6: revert GEMM to proven 128^2 m97-structure (R3); bf16 residual stream (kills 128MB f32
// write + 128MB f32 read); mem_scan 8-wide load batching.

typedef float  f32x4 __attribute__((ext_vector_type(4)));
typedef short  s16x8 __attribute__((ext_vector_type(8)));
typedef unsigned short u16x4 __attribute__((ext_vector_type(4)));

#define DEV static __device__ __forceinline__

constexpr int NR = 32768;          // L*BS

DEV float us2f(unsigned short u) {
  union { unsigned int i; float f; } z; z.i = ((unsigned int)u) << 16; return z.f;
}
DEV unsigned short f2bits(float f) {          // RNE f32 -> bf16 bits
  unsigned int u = __builtin_bit_cast(unsigned int, f);
  unsigned int r = u + 0x7fffu + ((u >> 16) & 1u);
  return (unsigned short)(r >> 16);
}

DEV void gload_lds16(const void* g, void* l) {
  __builtin_amdgcn_global_load_lds((__attribute__((address_space(1))) void*)g,
                                   (__attribute__((address_space(3))) void*)l, 16, 0, 0);
}

// ---------------- param prep: BN scale/shift + membrane betas ----------------
struct PrepArgs {
  const float *g[7], *b[7], *m[7], *v[7];   // bn1,bnq,bnk,bnv,bn2,bnf1,bnf2
  const float *wtq, *wtk;
  float *s[7], *t[7];
  float *betaq, *betak;
};

__global__ void prep_vectors(PrepArgs a) {
  int i = blockIdx.x * 256 + threadIdx.x;   // 0..2047
  const int dims[7] = {512, 512, 512, 512, 512, 2048, 512};
  #pragma unroll
  for (int k = 0; k < 7; ++k) {
    if (i < dims[k]) {
      float sc = a.g[k][i] * rsqrtf(a.v[k][i] + 1e-5f);
      a.s[k][i] = sc;
      a.t[k][i] = a.b[k][i] - a.m[k][i] * sc;
    }
  }
  if (i < 512) {
    float w = a.wtq[i];
    float sp = (w > 20.f) ? w : log1pf(expf(w));
    float be = 1.f - 1.f / (sp + 1.f);
    a.betaq[i] = fminf(fmaxf(be, 0.f), 0.9999f);
    w = a.wtk[i];
    sp = (w > 20.f) ? w : log1pf(expf(w));
    be = 1.f - 1.f / (sp + 1.f);
    a.betak[i] = fminf(fmaxf(be, 0.f), 0.9999f);
  }
}

// -------- fold W[K][N] -> WT bf16 [N][K] with scales; bias[j] = so*(sum_d tin*W + eb) + tout --------
__global__ void fold_wT(const float* __restrict__ W, int K, int Nn,
                        const float* scin, const float* scout,
                        const float* tin, const float* eb, const float* tout,
                        unsigned short* __restrict__ WT, float* bias) {
  int j = blockIdx.x;
  int lane = threadIdx.x;   // 64
  float so = scout ? scout[j] : 1.f;
  float dot = 0.f;
  for (int d = lane; d < K; d += 64) {
    float w = W[(size_t)d * Nn + j];
    float si = scin ? scin[d] : 1.f;
    WT[(size_t)j * K + d] = f2bits(w * si * so);
    if (tin) dot += tin[d] * w;
  }
  if (bias) {
    #pragma unroll
    for (int off = 32; off >= 1; off >>= 1) dot += __shfl_xor(dot, off);
    if (lane == 0) bias[j] = so * (dot + (eb ? eb[j] : 0.f)) + (tout ? tout[j] : 0.f);
  }
}

// ---------------- cast x f32 -> bf16 ----------------
__global__ void cast_x(const float* __restrict__ x, unsigned short* __restrict__ xb, int n) {
  int i = (blockIdx.x * blockDim.x + threadIdx.x) * 4;
  if (i >= n) return;
  float4 v = *(const float4*)(x + i);
  u16x4 o = {f2bits(v.x), f2bits(v.y), f2bits(v.z), f2bits(v.w)};
  *(u16x4*)(xb + i) = o;
}

__global__ void zero_f(float* __restrict__ p, int n) {
  int i = blockIdx.x * 256 + threadIdx.x;
  if (i < n) p[i] = 0.f;
}

// ---------------- GEMM: C[M,N] = A[M,K](bf16) * BT[N,K](bf16)^T + bias, fused epilogues --------
// MODE 0: outb = bf16(acc+bias)
// MODE 1: outb = bf16(xres_f32 + acc + bias)            (residual kept in bf16 only)
// MODE 2: outb = bf16(gelu(acc+bias))                   (sigmoid-form tanh gelu)
// MODE 3: outf = us2f(xresb) + acc + bias               (final f32 output)
template <int MODE>
__global__ __launch_bounds__(256, 2) void gemm_bf16(
    const unsigned short* __restrict__ A, const unsigned short* __restrict__ BT,
    int K, int Nn, const float* __restrict__ bias, const float* __restrict__ xres,
    const unsigned short* __restrict__ xresb,
    float* __restrict__ outf, unsigned short* __restrict__ outb) {
  __shared__ __align__(16) unsigned short Ab[2][128 * 32];
  __shared__ __align__(16) unsigned short Bb[2][128 * 32];
  const int tid = threadIdx.x, w = tid >> 6, lane = tid & 63;
  const int l15 = lane & 15, lg = lane >> 4;
  const int row0 = blockIdx.x * 128, col0 = blockIdx.y * 128;
  const int wr = w >> 1, wc = w & 1;
  const unsigned short* Abase = A + (size_t)row0 * K;
  const unsigned short* Bbase = BT + (size_t)col0 * K;

  auto stage = [&](int buf, int kt) {
    #pragma unroll
    for (int s = 0; s < 2; ++s) {
      int c = s * 256 + w * 64 + lane;
      gload_lds16(Abase + (size_t)(c >> 2) * K + kt * 32 + (c & 3) * 8,
                  &Ab[buf][(s * 256 + w * 64) * 8]);
      gload_lds16(Bbase + (size_t)(c >> 2) * K + kt * 32 + (c & 3) * 8,
                  &Bb[buf][(s * 256 + w * 64) * 8]);
    }
  };

  const f32x4 fz = {0.f, 0.f, 0.f, 0.f};
  f32x4 acc[4][4];
  #pragma unroll
  for (int m = 0; m < 4; ++m)
    #pragma unroll
    for (int n = 0; n < 4; ++n) acc[m][n] = fz;

  stage(0, 0);
  __syncthreads();
  int cur = 0;
  const int nt = K >> 5;
  for (int kt = 0; kt < nt; ++kt) {
    if (kt + 1 < nt) stage(cur ^ 1, kt + 1);
    s16x8 af[4], bf[4];
    #pragma unroll
    for (int m = 0; m < 4; ++m)
      af[m] = *(const s16x8*)&Ab[cur][(wr * 64 + m * 16 + l15) * 32 + lg * 8];
    #pragma unroll
    for (int n = 0; n < 4; ++n)
      bf[n] = *(const s16x8*)&Bb[cur][(wc * 64 + n * 16 + l15) * 32 + lg * 8];
    #pragma unroll
    for (int m = 0; m < 4; ++m)
      #pragma unroll
      for (int n = 0; n < 4; ++n)
        acc[m][n] = __builtin_amdgcn_mfma_f32_16x16x32_bf16(af[m], bf[n], acc[m][n], 0, 0, 0);
    __syncthreads();
    cur ^= 1;
  }

  #pragma unroll
  for (int m = 0; m < 4; ++m) {
    #pragma unroll
    for (int q = 0; q < 4; ++q) {
      int row = row0 + wr * 64 + m * 16 + lg * 4 + q;
      #pragma unroll
      for (int n = 0; n < 4; ++n) {
        int col = col0 + wc * 64 + n * 16 + l15;
        float v = acc[m][n][q] + bias[col];
        size_t idx = (size_t)row * Nn + col;
        if constexpr (MODE == 0) {
          outb[idx] = f2bits(v);
        } else if constexpr (MODE == 1) {
          outb[idx] = f2bits(xres[idx] + v);
        } else if constexpr (MODE == 2) {
          float u2 = v * 1.5957691216f * (1.f + 0.044715f * v * v);
          float gl = v / (1.f + __expf(-u2));
          outb[idx] = f2bits(gl);
        } else {
          outf[idx] = us2f(xresb[idx]) + v;
        }
      }
    }
  }
}

// ---------------- membrane EMA scan over L, IN-PLACE, coalesced, 8-wide batched ----------------
// qkv row = (l*16+b)*1536; channels 0..1023 = q cols then k cols (contiguous).
// Block: 1024 threads = 16 waves; wave w = L-chunk w (128 steps); lane = channel within 64-group.
__global__ __launch_bounds__(1024) void mem_scan2(unsigned short* __restrict__ qkv,
                         const float* __restrict__ betaq, const float* __restrict__ betak) {
  __shared__ float carry[16][64];
  __shared__ float pre[16][64];
  int cg = blockIdx.x & 15, b = blockIdx.x >> 4;
  int w = threadIdx.x >> 6, lane = threadIdx.x & 63;
  int ch = cg * 64 + lane;
  const float beta = (ch < 512) ? betaq[ch] : betak[ch - 512];
  const float om = 1.f - beta;
  unsigned short* base = qkv + (size_t)b * 1536 + ch;
  const size_t rs = 16 * 1536;     // shorts per L-step
  const int l0 = w * 128;

  float m = 0.f;
  for (int i = 0; i < 128; i += 8) {
    float v[8];
    #pragma unroll
    for (int j = 0; j < 8; ++j) v[j] = us2f(base[(size_t)(l0 + i + j) * rs]);
    #pragma unroll
    for (int j = 0; j < 8; ++j) m = beta * m + om * v[j];
  }
  carry[w][lane] = m;
  __syncthreads();
  if (w == 0) {
    float pw = beta;
    #pragma unroll
    for (int t = 0; t < 7; ++t) pw *= pw;   // beta^128
    float run = 0.f;
    for (int cc = 0; cc < 16; ++cc) {
      pre[cc][lane] = run;
      run = carry[cc][lane] + pw * run;
    }
  }
  __syncthreads();
  m = pre[w][lane];
  for (int i = 0; i < 128; i += 8) {
    float v[8];
    #pragma unroll
    for (int j = 0; j < 8; ++j) v[j] = us2f(base[(size_t)(l0 + i + j) * rs]);
    #pragma unroll
    for (int j = 0; j < 8; ++j) {
      m = beta * m + om * v[j];
      base[(size_t)(l0 + i + j) * rs] = f2bits(m);
    }
  }
}

// ---------------- transpose v: qkv v-cols -> vT[b,h,dh][L] ----------------
__global__ void transpose_v(const unsigned short* __restrict__ qkv, unsigned short* __restrict__ vT) {
  __shared__ __align__(16) unsigned short tile[64][72];
  int bid = blockIdx.x;
  int lt = bid & 31, h = (bid >> 5) & 7, b = bid >> 8;
  int l0 = lt * 64;
  int tid = threadIdx.x;
  int r = tid >> 2, cg = (tid & 3) * 16;
  const unsigned short* src = qkv + (size_t)((l0 + r) * 16 + b) * 1536 + 1024 + h * 64 + cg;
  *(s16x8*)&tile[r][cg] = *(const s16x8*)(src);
  *(s16x8*)&tile[r][cg + 8] = *(const s16x8*)(src + 8);
  __syncthreads();
  int dh = tid >> 2, lgp = (tid & 3) * 16;
  s16x8 o0, o1;
  #pragma unroll
  for (int j = 0; j < 8; ++j) {
    o0[j] = (short)tile[lgp + j][dh];
    o1[j] = (short)tile[lgp + 8 + j][dh];
  }
  unsigned short* dstp = vT + (size_t)((b * 8 + h) * 64 + dh) * 2048 + l0 + lgp;
  *(s16x8*)dstp = o0;
  *(s16x8*)(dstp + 8) = o1;
}

// ---------------- RFF linear attention phase A: KV + Ksum accumulation ----------------
__global__ __launch_bounds__(512, 1) void attn_A(
    const unsigned short* __restrict__ qkv, const unsigned short* __restrict__ vT,
    const unsigned short* __restrict__ WrT, const float* __restrict__ rffb,
    float* __restrict__ KVg, float* __restrict__ Ksumg) {
  __shared__ float KV[48][64];
  __shared__ float Ksum[48];
  __shared__ __align__(16) unsigned short phiT[8][48][72];

  const int tid = threadIdx.x;
  const int w = tid >> 6, lane = tid & 63, l15 = lane & 15, lg = lane >> 4;
  const int bh = blockIdx.x, b = bh >> 3, h = bh & 7;
  const int half = blockIdx.y;
  const f32x4 fz = {0.f, 0.f, 0.f, 0.f};
  constexpr float ISR = 0.14433756729740643f;   // 1/sqrt(48)

  for (int i = tid; i < 48 * 64; i += 512) (&KV[0][0])[i] = 0.f;
  if (tid < 48) Ksum[tid] = 0.f;
  __syncthreads();

  s16x8 wf[3][2];
  float bias_n[3];
  #pragma unroll
  for (int n = 0; n < 3; ++n) {
    int r = n * 16 + l15;
    bias_n[n] = rffb[h * 48 + r];
    #pragma unroll
    for (int ks = 0; ks < 2; ++ks)
      wf[n][ks] = *(const s16x8*)(WrT + (size_t)(h * 48 + r) * 64 + ks * 32 + lg * 8);
  }

  f32x4 kv[3][4];
  #pragma unroll
  for (int mm = 0; mm < 3; ++mm)
    #pragma unroll
    for (int nn = 0; nn < 4; ++nn) kv[mm][nn] = fz;
  float ks_acc[3] = {0.f, 0.f, 0.f};
  const size_t vbase = (size_t)(b * 8 + h) * 64 * 2048;

  for (int c = half * 16 + w; c < half * 16 + 16; c += 8) {
    const int l0 = c * 64;
    s16x8 kf[4][2];
    #pragma unroll
    for (int m = 0; m < 4; ++m) {
      size_t ro = (size_t)((l0 + m * 16 + l15) * 16 + b) * 1536 + 512 + h * 64;
      #pragma unroll
      for (int ks = 0; ks < 2; ++ks)
        kf[m][ks] = *(const s16x8*)(qkv + ro + ks * 32 + lg * 8);
    }
    f32x4 p[4][3];
    #pragma unroll
    for (int m = 0; m < 4; ++m)
      #pragma unroll
      for (int n = 0; n < 3; ++n) {
        p[m][n] = fz + bias_n[n];
        #pragma unroll
        for (int ks = 0; ks < 2; ++ks)
          p[m][n] = __builtin_amdgcn_mfma_f32_16x16x32_bf16(kf[m][ks], wf[n][ks], p[m][n], 0, 0, 0);
      }
    #pragma unroll
    for (int m = 0; m < 4; ++m)
      #pragma unroll
      for (int n = 0; n < 3; ++n) {
        u16x4 pk;
        #pragma unroll
        for (int q = 0; q < 4; ++q) {
          float pv = p[m][n][q];
          float ph = (pv > 0.f ? pv + 1.000001f : __expf(pv) + 1e-6f) * ISR;
          ks_acc[n] += ph;
          pk[q] = f2bits(ph);
        }
        *(u16x4*)&phiT[w][n * 16 + l15][m * 16 + lg * 4] = pk;
      }
    s16x8 pf[3][2], vf[4][2];
    #pragma unroll
    for (int mm = 0; mm < 3; ++mm)
      #pragma unroll
      for (int ks = 0; ks < 2; ++ks)
        pf[mm][ks] = *(const s16x8*)&phiT[w][mm * 16 + l15][ks * 32 + lg * 8];
    #pragma unroll
    for (int nn = 0; nn < 4; ++nn)
      #pragma unroll
      for (int ks = 0; ks < 2; ++ks)
        vf[nn][ks] = *(const s16x8*)(vT + vbase + (size_t)(nn * 16 + l15) * 2048 + l0 + ks * 32 + lg * 8);
    #pragma unroll
    for (int mm = 0; mm < 3; ++mm)
      #pragma unroll
      for (int nn = 0; nn < 4; ++nn)
        #pragma unroll
        for (int ks = 0; ks < 2; ++ks)
          kv[mm][nn] = __builtin_amdgcn_mfma_f32_16x16x32_bf16(pf[mm][ks], vf[nn][ks], kv[mm][nn], 0, 0, 0);
  }
  #pragma unroll
  for (int n = 0; n < 3; ++n) {
    float t = ks_acc[n];
    t += __shfl_xor(t, 16);
    t += __shfl_xor(t, 32);
    if (lane < 16) atomicAdd(&Ksum[n * 16 + lane], t);
  }
  #pragma unroll
  for (int mm = 0; mm < 3; ++mm)
    #pragma unroll
    for (int nn = 0; nn < 4; ++nn)
      #pragma unroll
      for (int q = 0; q < 4; ++q)
        atomicAdd(&KV[mm * 16 + lg * 4 + q][nn * 16 + l15], kv[mm][nn][q]);
  __syncthreads();

  for (int i = tid; i < 48 * 64; i += 512) atomicAdd(&KVg[(size_t)bh * 3072 + i], (&KV[0][0])[i]);
  if (tid < 48) atomicAdd(&Ksumg[bh * 48 + tid], Ksum[tid]);
}

// ---------------- RFF linear attention phase B: phi_q, num/den, output ----------------
__global__ __launch_bounds__(512, 1) void attn_B(
    const unsigned short* __restrict__ qkv, const unsigned short* __restrict__ WrT,
    const float* __restrict__ rffb, const float* __restrict__ KVg,
    const float* __restrict__ Ksumg, unsigned short* __restrict__ attn) {
  __shared__ __align__(16) unsigned short KVT[80][72];
  __shared__ __align__(16) unsigned short phiQ[8][64][72];

  const int tid = threadIdx.x;
  const int w = tid >> 6, lane = tid & 63, l15 = lane & 15, lg = lane >> 4;
  const int bh = blockIdx.x, b = bh >> 3, h = bh & 7;
  const int half = blockIdx.y;
  const f32x4 fz = {0.f, 0.f, 0.f, 0.f};
  constexpr float ISR = 0.14433756729740643f;   // 1/sqrt(48)

  for (int i = tid; i < 8 * 64 * 72; i += 512) (&phiQ[0][0][0])[i] = 0;
  for (int i = tid; i < 80 * 72; i += 512) {
    int dhe = i / 72, rr = i - dhe * 72;
    float val = 0.f;
    if (rr < 48) {
      if (dhe < 64) val = KVg[(size_t)bh * 3072 + rr * 64 + dhe];
      else if (dhe == 64) val = fmaxf(Ksumg[bh * 48 + rr], 1e-6f);
    }
    (&KVT[0][0])[i] = f2bits(val);
  }
  __syncthreads();

  s16x8 wf[3][2];
  float bias_n[3];
  #pragma unroll
  for (int n = 0; n < 3; ++n) {
    int r = n * 16 + l15;
    bias_n[n] = rffb[h * 48 + r];
    #pragma unroll
    for (int ks = 0; ks < 2; ++ks)
      wf[n][ks] = *(const s16x8*)(WrT + (size_t)(h * 48 + r) * 64 + ks * 32 + lg * 8);
  }

  for (int c = half * 16 + w; c < half * 16 + 16; c += 8) {
    const int l0 = c * 64;
    s16x8 qf[4][2];
    #pragma unroll
    for (int m = 0; m < 4; ++m) {
      size_t ro = (size_t)((l0 + m * 16 + l15) * 16 + b) * 1536 + h * 64;
      #pragma unroll
      for (int ks = 0; ks < 2; ++ks)
        qf[m][ks] = *(const s16x8*)(qkv + ro + ks * 32 + lg * 8);
    }
    f32x4 p[4][3];
    #pragma unroll
    for (int m = 0; m < 4; ++m)
      #pragma unroll
      for (int n = 0; n < 3; ++n) {
        p[m][n] = fz + bias_n[n];
        #pragma unroll
        for (int ks = 0; ks < 2; ++ks)
          p[m][n] = __builtin_amdgcn_mfma_f32_16x16x32_bf16(qf[m][ks], wf[n][ks], p[m][n], 0, 0, 0);
      }
    #pragma unroll
    for (int m = 0; m < 4; ++m)
      #pragma unroll
      for (int n = 0; n < 3; ++n)
        #pragma unroll
        for (int q = 0; q < 4; ++q) {
          float pv = p[m][n][q];
          float ph = (pv > 0.f ? pv + 1.000001f : __expf(pv) + 1e-6f) * ISR;
          phiQ[w][m * 16 + lg * 4 + q][n * 16 + l15] = f2bits(ph);
        }
    s16x8 af[4][2], bv8[5][2];
    #pragma unroll
    for (int m = 0; m < 4; ++m)
      #pragma unroll
      for (int ks = 0; ks < 2; ++ks)
        af[m][ks] = *(const s16x8*)&phiQ[w][m * 16 + l15][ks * 32 + lg * 8];
    #pragma unroll
    for (int n5 = 0; n5 < 5; ++n5)
      #pragma unroll
      for (int ks = 0; ks < 2; ++ks)
        bv8[n5][ks] = *(const s16x8*)&KVT[n5 * 16 + l15][ks * 32 + lg * 8];
    f32x4 o[4][5];
    #pragma unroll
    for (int m = 0; m < 4; ++m)
      #pragma unroll
      for (int n5 = 0; n5 < 5; ++n5) {
        o[m][n5] = fz;
        #pragma unroll
        for (int ks = 0; ks < 2; ++ks)
          o[m][n5] = __builtin_amdgcn_mfma_f32_16x16x32_bf16(af[m][ks], bv8[n5][ks], o[m][n5], 0, 0, 0);
      }
    #pragma unroll
    for (int m = 0; m < 4; ++m)
      #pragma unroll
      for (int q = 0; q < 4; ++q) {
        float den = __shfl(o[m][4][q], lane & 48);
        float inv = 1.f / (den + 1e-6f);
        int gl = l0 + m * 16 + lg * 4 + q;
        size_t ob = (size_t)(gl * 16 + b) * 512 + h * 64;
        #pragma unroll
        for (int n = 0; n < 4; ++n)
          attn[ob + n * 16 + l15] = f2bits(o[m][n][q] * inv);
      }
  }
}

// ---------------- host ----------------
extern "C" void kernel_launch(void* const* d_in, const int* in_sizes, int n_in,
                              void* d_out, int out_size, void* d_ws, size_t ws_size,
                              hipStream_t stream) {
  (void)in_sizes; (void)n_in; (void)out_size; (void)ws_size;
  const float* x = (const float*)d_in[0];
  const float* Wq = (const float*)d_in[29];
  const float* Wk = (const float*)d_in[30];
  const float* Wv = (const float*)d_in[31];
  const float* bv = (const float*)d_in[32];
  const float* Wo = (const float*)d_in[33];
  const float* bo = (const float*)d_in[34];
  const float* wtq = (const float*)d_in[35];
  const float* wtk = (const float*)d_in[36];
  const float* rffW = (const float*)d_in[37];
  const float* rffb = (const float*)d_in[38];
  const float* fc1W = (const float*)d_in[39];
  const float* fc1b = (const float*)d_in[40];
  const float* fc2W = (const float*)d_in[41];
  const float* fc2b = (const float*)d_in[42];

  char* cur = (char*)d_ws;
  auto alloc = [&](size_t bytes) -> char* {
    char* r = cur;
    cur += (bytes + 255) & ~(size_t)255;
    return r;
  };
  float* sv_[7];
  float* tv_[7];
  const int dims[7] = {512, 512, 512, 512, 512, 2048, 512};
  for (int k = 0; k < 7; ++k) {
    sv_[k] = (float*)alloc(dims[k] * 4);
    tv_[k] = (float*)alloc(dims[k] * 4);
  }
  float* betaq = (float*)alloc(512 * 4);
  float* betak = (float*)alloc(512 * 4);
  float* c_qkv = (float*)alloc(1536 * 4);
  float* c1 = (float*)alloc(2048 * 4);
  float* c2 = (float*)alloc(512 * 4);
  float* KVg   = (float*)alloc((size_t)128 * 3072 * 4);
  float* Ksumg = (float*)alloc((size_t)128 * 48 * 4);
  unsigned short* AqkvT = (unsigned short*)alloc((size_t)1536 * 512 * 2);
  unsigned short* WoT   = (unsigned short*)alloc((size_t)512 * 512 * 2);
  unsigned short* A1T   = (unsigned short*)alloc((size_t)2048 * 512 * 2);
  unsigned short* A2T   = (unsigned short*)alloc((size_t)512 * 2048 * 2);
  unsigned short* WrT   = (unsigned short*)alloc((size_t)8 * 48 * 64 * 2);
  // big buffers (qkv and vT MUST be adjacent: g overlays both exactly)
  unsigned short* qkv   = (unsigned short*)alloc((size_t)NR * 1536 * 2);  // 96 MiB
  unsigned short* vT    = (unsigned short*)alloc((size_t)NR * 512 * 2);   // 32 MiB
  unsigned short* xbA   = (unsigned short*)alloc((size_t)NR * 512 * 2);   // 32 MiB: xb then attn-out
  unsigned short* xrb   = (unsigned short*)alloc((size_t)NR * 512 * 2);   // 32 MiB
  unsigned short* xb = xbA;            // bf16(x), dead after QKV GEMM
  unsigned short* attn = xbA;          // attn output (after xb is dead)
  unsigned short* g = qkv;             // fc1-out [NR][2048] bf16 = 128 MiB over qkv+vT (both dead)

  PrepArgs pa;
  for (int k = 0; k < 7; ++k) {
    pa.g[k] = (const float*)d_in[1 + k * 4 + 0];
    pa.b[k] = (const float*)d_in[1 + k * 4 + 1];
    pa.m[k] = (const float*)d_in[1 + k * 4 + 2];
    pa.v[k] = (const float*)d_in[1 + k * 4 + 3];
    pa.s[k] = sv_[k];
    pa.t[k] = tv_[k];
  }
  pa.wtq = wtq; pa.wtk = wtk; pa.betaq = betaq; pa.betak = betak;

  prep_vectors<<<8, 256, 0, stream>>>(pa);
  fold_wT<<<512, 64, 0, stream>>>(Wq, 512, 512, sv_[0], sv_[1], tv_[0], nullptr, tv_[1], AqkvT, c_qkv);
  fold_wT<<<512, 64, 0, stream>>>(Wk, 512, 512, sv_[0], sv_[2], tv_[0], nullptr, tv_[2], AqkvT + 512 * 512, c_qkv + 512);
  fold_wT<<<512, 64, 0, stream>>>(Wv, 512, 512, sv_[0], sv_[3], tv_[0], bv, tv_[3], AqkvT + 1024 * 512, c_qkv + 1024);
  fold_wT<<<512, 64, 0, stream>>>(Wo, 512, 512, nullptr, nullptr, nullptr, nullptr, nullptr, WoT, nullptr);
  fold_wT<<<2048, 64, 0, stream>>>(fc1W, 512, 2048, sv_[4], sv_[5], tv_[4], fc1b, tv_[5], A1T, c1);
  fold_wT<<<512, 64, 0, stream>>>(fc2W, 2048, 512, nullptr, sv_[6], nullptr, fc2b, tv_[6], A2T, c2);
  for (int h = 0; h < 8; ++h)
    fold_wT<<<48, 64, 0, stream>>>(rffW + h * 64 * 48, 64, 48, nullptr, nullptr, nullptr, nullptr, nullptr,
                                   WrT + h * 48 * 64, nullptr);

  cast_x<<<16384, 256, 0, stream>>>(x, xb, NR * 512);
  gemm_bf16<0><<<dim3(256, 12), 256, 0, stream>>>(xb, AqkvT, 512, 1536, c_qkv, nullptr, nullptr, nullptr, qkv);
  mem_scan2<<<256, 1024, 0, stream>>>(qkv, betaq, betak);
  transpose_v<<<4096, 256, 0, stream>>>(qkv, vT);
  zero_f<<<1536, 256, 0, stream>>>(KVg, 128 * 3072);
  zero_f<<<24, 256, 0, stream>>>(Ksumg, 128 * 48);
  attn_A<<<dim3(128, 2), 512, 0, stream>>>(qkv, vT, WrT, rffb, KVg, Ksumg);
  attn_B<<<dim3(128, 2), 512, 0, stream>>>(qkv, WrT, rffb, KVg, Ksumg, attn);
  gemm_bf16<1><<<dim3(256, 4), 256, 0, stream>>>(attn, WoT, 512, 512, bo, x, nullptr, nullptr, xrb);
  gemm_bf16<2><<<dim3(256, 16), 256, 0, stream>>>(xrb, A1T, 512, 2048, c1, nullptr, nullptr, nullptr, g);
  gemm_bf16<3><<<dim3(256, 4), 256, 0, stream>>>(g, A2T, 2048, 512, c2, nullptr, xrb, (float*)d_out, nullptr);
}

// Round 7
// 562.627 us; speedup vs baseline: 1.0938x; 1.0009x over previous
//
#include <hip/hip_runtime.h>
#include <hip/hip_bf16.h>
#include <cstdint>
#include <math.h>

// SEDformer block: BN-folded bf16 MFMA GEMMs + in-place chunked EMA scan + RFF linear attention.
// L=2048 BS=16 D=512 H=8 DH=64 R=48 HID=2048; rows NR = L*BS = 32768.
// R7: XCD-chunk swizzle on GEMM+fold grids (T1); attn without global atomics/zero_f;
// attn-out lives in dead vT buffer; wo residual from bf16 xb.

typedef float  f32x4 __attribute__((ext_vector_type(4)));
typedef short  s16x8 __attribute__((ext_vector_type(8)));
typedef unsigned short u16x4 __attribute__((ext_vector_type(4)));

#define DEV static __device__ __forceinline__

constexpr int NR = 32768;          // L*BS

DEV float us2f(unsigned short u) {
  union { unsigned int i; float f; } z; z.i = ((unsigned int)u) << 16; return z.f;
}
DEV unsigned short f2bits(float f) {          // RNE f32 -> bf16 bits
  unsigned int u = __builtin_bit_cast(unsigned int, f);
  unsigned int r = u + 0x7fffu + ((u >> 16) & 1u);
  return (unsigned short)(r >> 16);
}

DEV void gload_lds16(const void* g, void* l) {
  __builtin_amdgcn_global_load_lds((__attribute__((address_space(1))) void*)g,
                                   (__attribute__((address_space(3))) void*)l, 16, 0, 0);
}

// ---------------- param prep: BN scale/shift + membrane betas ----------------
struct PrepArgs {
  const float *g[7], *b[7], *m[7], *v[7];   // bn1,bnq,bnk,bnv,bn2,bnf1,bnf2
  const float *wtq, *wtk;
  float *s[7], *t[7];
  float *betaq, *betak;
};

__global__ void prep_vectors(PrepArgs a) {
  int i = blockIdx.x * 256 + threadIdx.x;   // 0..2047
  const int dims[7] = {512, 512, 512, 512, 512, 2048, 512};
  #pragma unroll
  for (int k = 0; k < 7; ++k) {
    if (i < dims[k]) {
      float sc = a.g[k][i] * rsqrtf(a.v[k][i] + 1e-5f);
      a.s[k][i] = sc;
      a.t[k][i] = a.b[k][i] - a.m[k][i] * sc;
    }
  }
  if (i < 512) {
    float w = a.wtq[i];
    float sp = (w > 20.f) ? w : log1pf(expf(w));
    float be = 1.f - 1.f / (sp + 1.f);
    a.betaq[i] = fminf(fmaxf(be, 0.f), 0.9999f);
    w = a.wtk[i];
    sp = (w > 20.f) ? w : log1pf(expf(w));
    be = 1.f - 1.f / (sp + 1.f);
    a.betak[i] = fminf(fmaxf(be, 0.f), 0.9999f);
  }
}

// -------- fold W[K][N] -> WT bf16 [N][K] with scales; bias[j] = so*(sum_d tin*W + eb) + tout --------
// Grid swizzled so consecutive-j blocks land on the same XCD (share W cache lines).
__global__ void fold_wT(const float* __restrict__ W, int K, int Nn,
                        const float* scin, const float* scout,
                        const float* tin, const float* eb, const float* tout,
                        unsigned short* __restrict__ WT, float* bias) {
  int nb = gridDim.x, bid = blockIdx.x;
  int j = bid;
  if ((nb & 7) == 0) { int ch = nb >> 3; j = (bid & 7) * ch + (bid >> 3); }
  int lane = threadIdx.x;   // 64
  float so = scout ? scout[j] : 1.f;
  float dot = 0.f;
  for (int d = lane; d < K; d += 64) {
    float w = W[(size_t)d * Nn + j];
    float si = scin ? scin[d] : 1.f;
    WT[(size_t)j * K + d] = f2bits(w * si * so);
    if (tin) dot += tin[d] * w;
  }
  if (bias) {
    #pragma unroll
    for (int off = 32; off >= 1; off >>= 1) dot += __shfl_xor(dot, off);
    if (lane == 0) bias[j] = so * (dot + (eb ? eb[j] : 0.f)) + (tout ? tout[j] : 0.f);
  }
}

// ---------------- cast x f32 -> bf16 ----------------
__global__ void cast_x(const float* __restrict__ x, unsigned short* __restrict__ xb, int n) {
  int i = (blockIdx.x * blockDim.x + threadIdx.x) * 4;
  if (i >= n) return;
  float4 v = *(const float4*)(x + i);
  u16x4 o = {f2bits(v.x), f2bits(v.y), f2bits(v.z), f2bits(v.w)};
  *(u16x4*)(xb + i) = o;
}

// ---------------- GEMM: C[M,N] = A[M,K](bf16) * BT[N,K](bf16)^T + bias, fused epilogues --------
// 1D grid, XCD-chunk swizzle: orig = (wg&7)*(nwg/8) + wg>>3; bx = orig&255, by = orig>>8.
// MODE 0: outb = bf16(acc+bias)
// MODE 1: outb = bf16(us2f(xresb) + acc + bias)
// MODE 2: outb = bf16(gelu(acc+bias))   (sigmoid-form tanh gelu)
// MODE 3: outf = us2f(xresb) + acc + bias
template <int MODE>
__global__ __launch_bounds__(256, 2) void gemm_bf16(
    const unsigned short* __restrict__ A, const unsigned short* __restrict__ BT,
    int K, int Nn, const float* __restrict__ bias,
    const unsigned short* __restrict__ xresb,
    float* __restrict__ outf, unsigned short* __restrict__ outb) {
  __shared__ __align__(16) unsigned short Ab[2][128 * 32];
  __shared__ __align__(16) unsigned short Bb[2][128 * 32];
  const int tid = threadIdx.x, w = tid >> 6, lane = tid & 63;
  const int l15 = lane & 15, lg = lane >> 4;
  const int wg = blockIdx.x;
  const int chunk = gridDim.x >> 3;
  const int orig = (wg & 7) * chunk + (wg >> 3);
  const int row0 = (orig & 255) * 128, col0 = (orig >> 8) * 128;
  const int wr = w >> 1, wc = w & 1;
  const unsigned short* Abase = A + (size_t)row0 * K;
  const unsigned short* Bbase = BT + (size_t)col0 * K;

  auto stage = [&](int buf, int kt) {
    #pragma unroll
    for (int s = 0; s < 2; ++s) {
      int c = s * 256 + w * 64 + lane;
      gload_lds16(Abase + (size_t)(c >> 2) * K + kt * 32 + (c & 3) * 8,
                  &Ab[buf][(s * 256 + w * 64) * 8]);
      gload_lds16(Bbase + (size_t)(c >> 2) * K + kt * 32 + (c & 3) * 8,
                  &Bb[buf][(s * 256 + w * 64) * 8]);
    }
  };

  const f32x4 fz = {0.f, 0.f, 0.f, 0.f};
  f32x4 acc[4][4];
  #pragma unroll
  for (int m = 0; m < 4; ++m)
    #pragma unroll
    for (int n = 0; n < 4; ++n) acc[m][n] = fz;

  stage(0, 0);
  __syncthreads();
  int cur = 0;
  const int nt = K >> 5;
  for (int kt = 0; kt < nt; ++kt) {
    if (kt + 1 < nt) stage(cur ^ 1, kt + 1);
    s16x8 af[4], bf[4];
    #pragma unroll
    for (int m = 0; m < 4; ++m)
      af[m] = *(const s16x8*)&Ab[cur][(wr * 64 + m * 16 + l15) * 32 + lg * 8];
    #pragma unroll
    for (int n = 0; n < 4; ++n)
      bf[n] = *(const s16x8*)&Bb[cur][(wc * 64 + n * 16 + l15) * 32 + lg * 8];
    #pragma unroll
    for (int m = 0; m < 4; ++m)
      #pragma unroll
      for (int n = 0; n < 4; ++n)
        acc[m][n] = __builtin_amdgcn_mfma_f32_16x16x32_bf16(af[m], bf[n], acc[m][n], 0, 0, 0);
    __syncthreads();
    cur ^= 1;
  }

  #pragma unroll
  for (int m = 0; m < 4; ++m) {
    #pragma unroll
    for (int q = 0; q < 4; ++q) {
      int row = row0 + wr * 64 + m * 16 + lg * 4 + q;
      #pragma unroll
      for (int n = 0; n < 4; ++n) {
        int col = col0 + wc * 64 + n * 16 + l15;
        float v = acc[m][n][q] + bias[col];
        size_t idx = (size_t)row * Nn + col;
        if constexpr (MODE == 0) {
          outb[idx] = f2bits(v);
        } else if constexpr (MODE == 1) {
          outb[idx] = f2bits(us2f(xresb[idx]) + v);
        } else if constexpr (MODE == 2) {
          float u2 = v * 1.5957691216f * (1.f + 0.044715f * v * v);
          float gl = v / (1.f + __expf(-u2));
          outb[idx] = f2bits(gl);
        } else {
          outf[idx] = us2f(xresb[idx]) + v;
        }
      }
    }
  }
}

// ---------------- membrane EMA scan over L, IN-PLACE, coalesced, 8-wide batched ----------------
__global__ __launch_bounds__(1024) void mem_scan2(unsigned short* __restrict__ qkv,
                         const float* __restrict__ betaq, const float* __restrict__ betak) {
  __shared__ float carry[16][64];
  __shared__ float pre[16][64];
  int cg = blockIdx.x & 15, b = blockIdx.x >> 4;
  int w = threadIdx.x >> 6, lane = threadIdx.x & 63;
  int ch = cg * 64 + lane;
  const float beta = (ch < 512) ? betaq[ch] : betak[ch - 512];
  const float om = 1.f - beta;
  unsigned short* base = qkv + (size_t)b * 1536 + ch;
  const size_t rs = 16 * 1536;     // shorts per L-step
  const int l0 = w * 128;

  float m = 0.f;
  for (int i = 0; i < 128; i += 8) {
    float v[8];
    #pragma unroll
    for (int j = 0; j < 8; ++j) v[j] = us2f(base[(size_t)(l0 + i + j) * rs]);
    #pragma unroll
    for (int j = 0; j < 8; ++j) m = beta * m + om * v[j];
  }
  carry[w][lane] = m;
  __syncthreads();
  if (w == 0) {
    float pw = beta;
    #pragma unroll
    for (int t = 0; t < 7; ++t) pw *= pw;   // beta^128
    float run = 0.f;
    for (int cc = 0; cc < 16; ++cc) {
      pre[cc][lane] = run;
      run = carry[cc][lane] + pw * run;
    }
  }
  __syncthreads();
  m = pre[w][lane];
  for (int i = 0; i < 128; i += 8) {
    float v[8];
    #pragma unroll
    for (int j = 0; j < 8; ++j) v[j] = us2f(base[(size_t)(l0 + i + j) * rs]);
    #pragma unroll
    for (int j = 0; j < 8; ++j) {
      m = beta * m + om * v[j];
      base[(size_t)(l0 + i + j) * rs] = f2bits(m);
    }
  }
}

// ---------------- transpose v: qkv v-cols -> vT[b,h,dh][L] ----------------
__global__ void transpose_v(const unsigned short* __restrict__ qkv, unsigned short* __restrict__ vT) {
  __shared__ __align__(16) unsigned short tile[64][72];
  int bid = blockIdx.x;
  int lt = bid & 31, h = (bid >> 5) & 7, b = bid >> 8;
  int l0 = lt * 64;
  int tid = threadIdx.x;
  int r = tid >> 2, cg = (tid & 3) * 16;
  const unsigned short* src = qkv + (size_t)((l0 + r) * 16 + b) * 1536 + 1024 + h * 64 + cg;
  *(s16x8*)&tile[r][cg] = *(const s16x8*)(src);
  *(s16x8*)&tile[r][cg + 8] = *(const s16x8*)(src + 8);
  __syncthreads();
  int dh = tid >> 2, lgp = (tid & 3) * 16;
  s16x8 o0, o1;
  #pragma unroll
  for (int j = 0; j < 8; ++j) {
    o0[j] = (short)tile[lgp + j][dh];
    o1[j] = (short)tile[lgp + 8 + j][dh];
  }
  unsigned short* dstp = vT + (size_t)((b * 8 + h) * 64 + dh) * 2048 + l0 + lgp;
  *(s16x8*)dstp = o0;
  *(s16x8*)(dstp + 8) = o1;
}

// ---------------- RFF linear attention phase A: KV + Ksum partials (no global atomics) ----------
// grid (128 bh, 2 half); each (bh,half) block writes its own KVg/Ksumg slice.
__global__ __launch_bounds__(512, 1) void attn_A(
    const unsigned short* __restrict__ qkv, const unsigned short* __restrict__ vT,
    const unsigned short* __restrict__ WrT, const float* __restrict__ rffb,
    float* __restrict__ KVg, float* __restrict__ Ksumg) {
  __shared__ float KV[48][64];
  __shared__ float Ksum[48];
  __shared__ __align__(16) unsigned short phiT[8][48][72];

  const int tid = threadIdx.x;
  const int w = tid >> 6, lane = tid & 63, l15 = lane & 15, lg = lane >> 4;
  const int bh = blockIdx.x, b = bh >> 3, h = bh & 7;
  const int half = blockIdx.y;
  const f32x4 fz = {0.f, 0.f, 0.f, 0.f};
  constexpr float ISR = 0.14433756729740643f;   // 1/sqrt(48)

  for (int i = tid; i < 48 * 64; i += 512) (&KV[0][0])[i] = 0.f;
  if (tid < 48) Ksum[tid] = 0.f;
  __syncthreads();

  s16x8 wf[3][2];
  float bias_n[3];
  #pragma unroll
  for (int n = 0; n < 3; ++n) {
    int r = n * 16 + l15;
    bias_n[n] = rffb[h * 48 + r];
    #pragma unroll
    for (int ks = 0; ks < 2; ++ks)
      wf[n][ks] = *(const s16x8*)(WrT + (size_t)(h * 48 + r) * 64 + ks * 32 + lg * 8);
  }

  f32x4 kv[3][4];
  #pragma unroll
  for (int mm = 0; mm < 3; ++mm)
    #pragma unroll
    for (int nn = 0; nn < 4; ++nn) kv[mm][nn] = fz;
  float ks_acc[3] = {0.f, 0.f, 0.f};
  const size_t vbase = (size_t)(b * 8 + h) * 64 * 2048;

  for (int c = half * 16 + w; c < half * 16 + 16; c += 8) {
    const int l0 = c * 64;
    s16x8 kf[4][2];
    #pragma unroll
    for (int m = 0; m < 4; ++m) {
      size_t ro = (size_t)((l0 + m * 16 + l15) * 16 + b) * 1536 + 512 + h * 64;
      #pragma unroll
      for (int ks = 0; ks < 2; ++ks)
        kf[m][ks] = *(const s16x8*)(qkv + ro + ks * 32 + lg * 8);
    }
    f32x4 p[4][3];
    #pragma unroll
    for (int m = 0; m < 4; ++m)
      #pragma unroll
      for (int n = 0; n < 3; ++n) {
        p[m][n] = fz + bias_n[n];
        #pragma unroll
        for (int ks = 0; ks < 2; ++ks)
          p[m][n] = __builtin_amdgcn_mfma_f32_16x16x32_bf16(kf[m][ks], wf[n][ks], p[m][n], 0, 0, 0);
      }
    #pragma unroll
    for (int m = 0; m < 4; ++m)
      #pragma unroll
      for (int n = 0; n < 3; ++n) {
        u16x4 pk;
        #pragma unroll
        for (int q = 0; q < 4; ++q) {
          float pv = p[m][n][q];
          float ph = (pv > 0.f ? pv + 1.000001f : __expf(pv) + 1e-6f) * ISR;
          ks_acc[n] += ph;
          pk[q] = f2bits(ph);
        }
        *(u16x4*)&phiT[w][n * 16 + l15][m * 16 + lg * 4] = pk;
      }
    s16x8 pf[3][2], vf[4][2];
    #pragma unroll
    for (int mm = 0; mm < 3; ++mm)
      #pragma unroll
      for (int ks = 0; ks < 2; ++ks)
        pf[mm][ks] = *(const s16x8*)&phiT[w][mm * 16 + l15][ks * 32 + lg * 8];
    #pragma unroll
    for (int nn = 0; nn < 4; ++nn)
      #pragma unroll
      for (int ks = 0; ks < 2; ++ks)
        vf[nn][ks] = *(const s16x8*)(vT + vbase + (size_t)(nn * 16 + l15) * 2048 + l0 + ks * 32 + lg * 8);
    #pragma unroll
    for (int mm = 0; mm < 3; ++mm)
      #pragma unroll
      for (int nn = 0; nn < 4; ++nn)
        #pragma unroll
        for (int ks = 0; ks < 2; ++ks)
          kv[mm][nn] = __builtin_amdgcn_mfma_f32_16x16x32_bf16(pf[mm][ks], vf[nn][ks], kv[mm][nn], 0, 0, 0);
  }
  #pragma unroll
  for (int n = 0; n < 3; ++n) {
    float t = ks_acc[n];
    t += __shfl_xor(t, 16);
    t += __shfl_xor(t, 32);
    if (lane < 16) atomicAdd(&Ksum[n * 16 + lane], t);
  }
  #pragma unroll
  for (int mm = 0; mm < 3; ++mm)
    #pragma unroll
    for (int nn = 0; nn < 4; ++nn)
      #pragma unroll
      for (int q = 0; q < 4; ++q)
        atomicAdd(&KV[mm * 16 + lg * 4 + q][nn * 16 + l15], kv[mm][nn][q]);
  __syncthreads();

  // non-atomic flush to this block's own slice
  float* dst = KVg + (size_t)(half * 128 + bh) * 3072;
  for (int i = tid; i < 48 * 64; i += 512) dst[i] = (&KV[0][0])[i];
  if (tid < 48) Ksumg[(half * 128 + bh) * 48 + tid] = Ksum[tid];
}

// ---------------- RFF linear attention phase B: phi_q, num/den, output ----------------
__global__ __launch_bounds__(512, 1) void attn_B(
    const unsigned short* __restrict__ qkv, const unsigned short* __restrict__ WrT,
    const float* __restrict__ rffb, const float* __restrict__ KVg,
    const float* __restrict__ Ksumg, unsigned short* __restrict__ attn) {
  __shared__ __align__(16) unsigned short KVT[80][72];
  __shared__ __align__(16) unsigned short phiQ[8][64][72];

  const int tid = threadIdx.x;
  const int w = tid >> 6, lane = tid & 63, l15 = lane & 15, lg = lane >> 4;
  const int bh = blockIdx.x, b = bh >> 3, h = bh & 7;
  const int half = blockIdx.y;
  const f32x4 fz = {0.f, 0.f, 0.f, 0.f};
  constexpr float ISR = 0.14433756729740643f;   // 1/sqrt(48)

  for (int i = tid; i < 8 * 64 * 72; i += 512) (&phiQ[0][0][0])[i] = 0;
  for (int i = tid; i < 80 * 72; i += 512) {
    int dhe = i / 72, rr = i - dhe * 72;
    float val = 0.f;
    if (rr < 48) {
      if (dhe < 64)
        val = KVg[(size_t)bh * 3072 + rr * 64 + dhe] + KVg[(size_t)(128 + bh) * 3072 + rr * 64 + dhe];
      else if (dhe == 64)
        val = fmaxf(Ksumg[bh * 48 + rr] + Ksumg[(128 + bh) * 48 + rr], 1e-6f);
    }
    (&KVT[0][0])[i] = f2bits(val);
  }
  __syncthreads();

  s16x8 wf[3][2];
  float bias_n[3];
  #pragma unroll
  for (int n = 0; n < 3; ++n) {
    int r = n * 16 + l15;
    bias_n[n] = rffb[h * 48 + r];
    #pragma unroll
    for (int ks = 0; ks < 2; ++ks)
      wf[n][ks] = *(const s16x8*)(WrT + (size_t)(h * 48 + r) * 64 + ks * 32 + lg * 8);
  }

  for (int c = half * 16 + w; c < half * 16 + 16; c += 8) {
    const int l0 = c * 64;
    s16x8 qf[4][2];
    #pragma unroll
    for (int m = 0; m < 4; ++m) {
      size_t ro = (size_t)((l0 + m * 16 + l15) * 16 + b) * 1536 + h * 64;
      #pragma unroll
      for (int ks = 0; ks < 2; ++ks)
        qf[m][ks] = *(const s16x8*)(qkv + ro + ks * 32 + lg * 8);
    }
    f32x4 p[4][3];
    #pragma unroll
    for (int m = 0; m < 4; ++m)
      #pragma unroll
      for (int n = 0; n < 3; ++n) {
        p[m][n] = fz + bias_n[n];
        #pragma unroll
        for (int ks = 0; ks < 2; ++ks)
          p[m][n] = __builtin_amdgcn_mfma_f32_16x16x32_bf16(qf[m][ks], wf[n][ks], p[m][n], 0, 0, 0);
      }
    #pragma unroll
    for (int m = 0; m < 4; ++m)
      #pragma unroll
      for (int n = 0; n < 3; ++n)
        #pragma unroll
        for (int q = 0; q < 4; ++q) {
          float pv = p[m][n][q];
          float ph = (pv > 0.f ? pv + 1.000001f : __expf(pv) + 1e-6f) * ISR;
          phiQ[w][m * 16 + lg * 4 + q][n * 16 + l15] = f2bits(ph);
        }
    s16x8 af[4][2], bv8[5][2];
    #pragma unroll
    for (int m = 0; m < 4; ++m)
      #pragma unroll
      for (int ks = 0; ks < 2; ++ks)
        af[m][ks] = *(const s16x8*)&phiQ[w][m * 16 + l15][ks * 32 + lg * 8];
    #pragma unroll
    for (int n5 = 0; n5 < 5; ++n5)
      #pragma unroll
      for (int ks = 0; ks < 2; ++ks)
        bv8[n5][ks] = *(const s16x8*)&KVT[n5 * 16 + l15][ks * 32 + lg * 8];
    f32x4 o[4][5];
    #pragma unroll
    for (int m = 0; m < 4; ++m)
      #pragma unroll
      for (int n5 = 0; n5 < 5; ++n5) {
        o[m][n5] = fz;
        #pragma unroll
        for (int ks = 0; ks < 2; ++ks)
          o[m][n5] = __builtin_amdgcn_mfma_f32_16x16x32_bf16(af[m][ks], bv8[n5][ks], o[m][n5], 0, 0, 0);
      }
    #pragma unroll
    for (int m = 0; m < 4; ++m)
      #pragma unroll
      for (int q = 0; q < 4; ++q) {
        float den = __shfl(o[m][4][q], lane & 48);
        float inv = 1.f / (den + 1e-6f);
        int gl = l0 + m * 16 + lg * 4 + q;
        size_t ob = (size_t)(gl * 16 + b) * 512 + h * 64;
        #pragma unroll
        for (int n = 0; n < 4; ++n)
          attn[ob + n * 16 + l15] = f2bits(o[m][n][q] * inv);
      }
  }
}

// ---------------- host ----------------
extern "C" void kernel_launch(void* const* d_in, const int* in_sizes, int n_in,
                              void* d_out, int out_size, void* d_ws, size_t ws_size,
                              hipStream_t stream) {
  (void)in_sizes; (void)n_in; (void)out_size; (void)ws_size;
  const float* x = (const float*)d_in[0];
  const float* Wq = (const float*)d_in[29];
  const float* Wk = (const float*)d_in[30];
  const float* Wv = (const float*)d_in[31];
  const float* bv = (const float*)d_in[32];
  const float* Wo = (const float*)d_in[33];
  const float* bo = (const float*)d_in[34];
  const float* wtq = (const float*)d_in[35];
  const float* wtk = (const float*)d_in[36];
  const float* rffW = (const float*)d_in[37];
  const float* rffb = (const float*)d_in[38];
  const float* fc1W = (const float*)d_in[39];
  const float* fc1b = (const float*)d_in[40];
  const float* fc2W = (const float*)d_in[41];
  const float* fc2b = (const float*)d_in[42];

  char* cur = (char*)d_ws;
  auto alloc = [&](size_t bytes) -> char* {
    char* r = cur;
    cur += (bytes + 255) & ~(size_t)255;
    return r;
  };
  float* sv_[7];
  float* tv_[7];
  const int dims[7] = {512, 512, 512, 512, 512, 2048, 512};
  for (int k = 0; k < 7; ++k) {
    sv_[k] = (float*)alloc(dims[k] * 4);
    tv_[k] = (float*)alloc(dims[k] * 4);
  }
  float* betaq = (float*)alloc(512 * 4);
  float* betak = (float*)alloc(512 * 4);
  float* c_qkv = (float*)alloc(1536 * 4);
  float* c1 = (float*)alloc(2048 * 4);
  float* c2 = (float*)alloc(512 * 4);
  float* KVg   = (float*)alloc((size_t)256 * 3072 * 4);   // [half*128+bh][3072]
  float* Ksumg = (float*)alloc((size_t)256 * 48 * 4);
  unsigned short* AqkvT = (unsigned short*)alloc((size_t)1536 * 512 * 2);
  unsigned short* WoT   = (unsigned short*)alloc((size_t)512 * 512 * 2);
  unsigned short* A1T   = (unsigned short*)alloc((size_t)2048 * 512 * 2);
  unsigned short* A2T   = (unsigned short*)alloc((size_t)512 * 2048 * 2);
  unsigned short* WrT   = (unsigned short*)alloc((size_t)8 * 48 * 64 * 2);
  // big buffers (qkv and vT MUST be adjacent: g overlays both exactly)
  unsigned short* qkv   = (unsigned short*)alloc((size_t)NR * 1536 * 2);  // 96 MiB
  unsigned short* vT    = (unsigned short*)alloc((size_t)NR * 512 * 2);   // 32 MiB: vT then attn-out
  unsigned short* xb    = (unsigned short*)alloc((size_t)NR * 512 * 2);   // 32 MiB: bf16(x), lives to wo
  unsigned short* xrb   = (unsigned short*)alloc((size_t)NR * 512 * 2);   // 32 MiB
  unsigned short* attnO = vT;          // attn output reuses vT (dead after attn_A)
  unsigned short* g = qkv;             // fc1-out [NR][2048] bf16 = 128 MiB over qkv+vT (both dead)

  PrepArgs pa;
  for (int k = 0; k < 7; ++k) {
    pa.g[k] = (const float*)d_in[1 + k * 4 + 0];
    pa.b[k] = (const float*)d_in[1 + k * 4 + 1];
    pa.m[k] = (const float*)d_in[1 + k * 4 + 2];
    pa.v[k] = (const float*)d_in[1 + k * 4 + 3];
    pa.s[k] = sv_[k];
    pa.t[k] = tv_[k];
  }
  pa.wtq = wtq; pa.wtk = wtk; pa.betaq = betaq; pa.betak = betak;

  prep_vectors<<<8, 256, 0, stream>>>(pa);
  fold_wT<<<512, 64, 0, stream>>>(Wq, 512, 512, sv_[0], sv_[1], tv_[0], nullptr, tv_[1], AqkvT, c_qkv);
  fold_wT<<<512, 64, 0, stream>>>(Wk, 512, 512, sv_[0], sv_[2], tv_[0], nullptr, tv_[2], AqkvT + 512 * 512, c_qkv + 512);
  fold_wT<<<512, 64, 0, stream>>>(Wv, 512, 512, sv_[0], sv_[3], tv_[0], bv, tv_[3], AqkvT + 1024 * 512, c_qkv + 1024);
  fold_wT<<<512, 64, 0, stream>>>(Wo, 512, 512, nullptr, nullptr, nullptr, nullptr, nullptr, WoT, nullptr);
  fold_wT<<<2048, 64, 0, stream>>>(fc1W, 512, 2048, sv_[4], sv_[5], tv_[4], fc1b, tv_[5], A1T, c1);
  fold_wT<<<512, 64, 0, stream>>>(fc2W, 2048, 512, nullptr, sv_[6], nullptr, fc2b, tv_[6], A2T, c2);
  for (int h = 0; h < 8; ++h)
    fold_wT<<<48, 64, 0, stream>>>(rffW + h * 64 * 48, 64, 48, nullptr, nullptr, nullptr, nullptr, nullptr,
                                   WrT + h * 48 * 64, nullptr);

  cast_x<<<16384, 256, 0, stream>>>(x, xb, NR * 512);
  gemm_bf16<0><<<3072, 256, 0, stream>>>(xb, AqkvT, 512, 1536, c_qkv, nullptr, nullptr, qkv);
  mem_scan2<<<256, 1024, 0, stream>>>(qkv, betaq, betak);
  transpose_v<<<4096, 256, 0, stream>>>(qkv, vT);
  attn_A<<<dim3(128, 2), 512, 0, stream>>>(qkv, vT, WrT, rffb, KVg, Ksumg);
  attn_B<<<dim3(128, 2), 512, 0, stream>>>(qkv, WrT, rffb, KVg, Ksumg, attnO);
  gemm_bf16<1><<<1024, 256, 0, stream>>>(attnO, WoT, 512, 512, bo, xb, nullptr, xrb);
  gemm_bf16<2><<<4096, 256, 0, stream>>>(xrb, A1T, 512, 2048, c1, nullptr, nullptr, g);
  gemm_bf16<3><<<1024, 256, 0, stream>>>(g, A2T, 2048, 512, c2, xrb, (float*)d_out, nullptr);
}